// Round 1
// baseline (309.346 us; speedup 1.0000x reference)
//
#include <hip/hip_runtime.h>
#include <hip/hip_cooperative_groups.h>
#include <math.h>

namespace cg = cooperative_groups;

// Problem constants
#define B_   64
#define T_   512
#define D_   96
#define TY_  512
#define H_   4
#define DK_  32
#define E_   128
#define P_   2
#define L_   64
#define HID_ 128

// Workspace layout (float offsets)
#define WS_OB2P  1024      // 8*64 : ob2 partials (const-half of ow, 8 slices)
#define WS_PN    2048      // 64b*8c*8hp*96f = 393216 : partial numerators
#define WS_PD    395264    // 393216 : partial denominators

// ---------------------------------------------------------------------------
// Shared-memory overlay: phase-1 (spool) buffers are dead before phase-2
// (decoder) buffers come alive (separated by grid.sync / kernel boundary),
// so alias them in one union. sizeof = 58,112 B -> 2 blocks/CU, which is
// exactly the residency of a 512-block grid on 256 CUs (no occupancy loss,
// and satisfies the cooperative-launch co-residency check).
// ---------------------------------------------------------------------------
struct SMemP1 {
    float qm[P_ * E_];
    float w2q[E_ * 8];
    float tw[E_], tb[E_], bq[8];
    float w[64 * 8];
    float red[96 * 17];    // stride 17: no bank conflicts
    float obp2[4][64];
};
struct SMemP2 {
    float w2s[HID_ * D_];  // 48 KB decoder weight tile
    float xa[8 * 96];
    float cfp[4][2][64];
    float cf[2][64];
    float a0[HID_], a1[HID_];
    float ys[64];
    float abp[2][2][128];
};
union SMem {
    SMemP1 p1;
    SMemP2 p2;
};

// ---------------------------------------------------------------------------
// Phase 1 (per block, bi in [0,512)): fused prep + scores + exp + pool.
//   c = bi & 7 (t-chunk), b = bi >> 3 (batch)
//   qm[p,e'] = query[p,:] @ q_w + q_b    (redundant per block, L2-hot)
//   w2q[e,hp] = sum_dk k_w[e,h*32+dk]*qm[p,h*32+dk]/sqrt(32);  bq likewise
// A: w[t,hp] = exp(emb(t) . w2q[:,hp] + bq[hp])   (no max-sub: |s|<~20)
// B: num[hp,f] += w*M*X ; den[hp,f] += w*M  over the 64-t chunk -> ws
// Epilogue (b==0): ob2 partial slice c (xa 2nd half == 1 -> bias fold)
// ---------------------------------------------------------------------------
__device__ __forceinline__ void phase1(
    SMem& sm, int bi, int tid,
    const float* __restrict__ tsteps, const float* __restrict__ te_w,
    const float* __restrict__ te_b,   const float* __restrict__ X,
    const float* __restrict__ M,      const float* __restrict__ query,
    const float* __restrict__ q_w,    const float* __restrict__ q_b,
    const float* __restrict__ k_w,    const float* __restrict__ k_b,
    const float* __restrict__ ow,     float* __restrict__ ws)
{
    const int c = bi & 7, b = bi >> 3;
    SMemP1& p1 = sm.p1;

    // ---- Prologue: fused q/k weights ----
    {
        int p = tid >> 7, ep = tid & 127;
        float acc = q_b[ep];
        #pragma unroll 4
        for (int e = 0; e < E_; ++e)
            acc += query[p * E_ + e] * q_w[e * E_ + ep];
        p1.qm[p * E_ + ep] = acc;
    }
    if (tid < E_) { p1.tw[tid] = te_w[tid]; p1.tb[tid] = te_b[tid]; }
    __syncthreads();
    const float rs = 0.17677669529663687f;  // 1/sqrt(32)
    #pragma unroll
    for (int i = 0; i < 4; ++i) {
        int idx = tid + i * 256;
        int e = idx >> 3, hp = idx & 7, h = hp >> 1, p = hp & 1;
        float acc = 0.f;
        #pragma unroll
        for (int dk = 0; dk < DK_; ++dk)
            acc += k_w[e * E_ + h * DK_ + dk] * p1.qm[p * E_ + h * DK_ + dk];
        p1.w2q[idx] = acc * rs;
    }
    if (tid < 8) {
        int hp = tid, h = hp >> 1, p = hp & 1;
        float acc = 0.f;
        #pragma unroll
        for (int dk = 0; dk < DK_; ++dk)
            acc += k_b[h * DK_ + dk] * p1.qm[p * E_ + h * DK_ + dk];
        p1.bq[hp] = acc * rs;
    }
    __syncthreads();

    // ---- Phase A: thread = (t in chunk, hp-pair) ----
    {
        const int t = tid & 63, hpg = tid >> 6, hp0 = hpg * 2;
        const float tv = tsteps[b * T_ + c * 64 + t];
        float a0 = 0.f, a1 = 0.f;
        #pragma unroll 4
        for (int e = 0; e < E_; ++e) {
            float v = tv * p1.tw[e] + p1.tb[e];
            if ((e & 3) == 0) v = __sinf(v);
            float2 w = *(const float2*)&p1.w2q[e * 8 + hp0];
            a0 += v * w.x;
            a1 += v * w.y;
        }
        p1.w[t * 8 + hp0]     = __expf(a0 + p1.bq[hp0]);
        p1.w[t * 8 + hp0 + 1] = __expf(a1 + p1.bq[hp0 + 1]);
    }
    __syncthreads();

    // ---- Phase B: 2 t-slices x 128 fid (96 active) ----
    const int fid = tid & 127, slice = tid >> 7;
    float num[8] = {0.f, 0.f, 0.f, 0.f, 0.f, 0.f, 0.f, 0.f};
    float den[8] = {0.f, 0.f, 0.f, 0.f, 0.f, 0.f, 0.f, 0.f};
    if (fid < 96) {
        #pragma unroll 4
        for (int i = 0; i < 32; ++i) {
            int tl = slice + 2 * i;
            size_t base = ((size_t)(b * T_ + c * 64 + tl)) * D_ + fid;
            float m = M[base], x = X[base];
            float mx = m * x;
            const float* wr = p1.w + tl * 8;
            #pragma unroll
            for (int hp = 0; hp < 8; ++hp) {
                num[hp] += wr[hp] * mx;
                den[hp] += wr[hp] * m;
            }
        }
    }
    __syncthreads();
    if (slice == 1 && fid < 96) {
        #pragma unroll
        for (int hp = 0; hp < 8; ++hp) {
            p1.red[fid * 17 + hp]     = num[hp];
            p1.red[fid * 17 + 8 + hp] = den[hp];
        }
    }
    __syncthreads();
    if (slice == 0 && fid < 96) {
        float* pN = ws + WS_PN + ((size_t)((b * 8 + c) * 8)) * 96;
        float* pD = ws + WS_PD + ((size_t)((b * 8 + c) * 8)) * 96;
        #pragma unroll
        for (int hp = 0; hp < 8; ++hp) {
            pN[hp * 96 + fid] = num[hp] + p1.red[fid * 17 + hp];
            pD[hp * 96 + fid] = den[hp] + p1.red[fid * 17 + 8 + hp];
        }
    }

    // ---- Epilogue (b==0 only): ob2 partial slice c over 48 (h,j) pairs ----
    if (b == 0) {
        int sub = tid >> 6, l = tid & 63;
        float acc = 0.f;
        #pragma unroll
        for (int k = 0; k < 12; ++k) {
            int hj = c * 48 + sub * 12 + k;
            int h = hj / 96, j = hj - h * 96;
            acc += ow[(size_t)(h * 2 * D_ + D_ + j) * L_ + l];
        }
        p1.obp2[sub][l] = acc;
        __syncthreads();
        if (sub == 0)
            ws[WS_OB2P + c * 64 + l] = p1.obp2[0][l] + p1.obp2[1][l]
                                     + p1.obp2[2][l] + p1.obp2[3][l];
    }
}

// ---------------------------------------------------------------------------
// Phase 2 (per block): partials -> xa -> coeffs -> a0/a1 (redundant x8 per b,
// cheap: ~50K MACs) then decoder GEMM for this block's 64 positions.
// w2 is prefetched into registers FIRST so the 48 KB global read overlaps
// the coefficient GEMVs; it lands in LDS just before the j-loop needs it.
// ---------------------------------------------------------------------------
__device__ __forceinline__ void phase2(
    SMem& sm, int bi, int tid,
    const float* __restrict__ ow, const float* __restrict__ ob,
    const float* __restrict__ w1, const float* __restrict__ b1,
    const float* __restrict__ yts, const float* __restrict__ w2,
    const float* __restrict__ b2, const float* __restrict__ ws,
    float* __restrict__ out)
{
    SMemP2& p2 = sm.p2;
    const int b = bi >> 3;

    // issue w2 prefetch (12 x float4/thread, coalesced) — consumed at (f)
    float4 wreg[12];
    {
        const float4* src = (const float4*)w2;
        #pragma unroll
        for (int i = 0; i < 12; ++i) wreg[i] = src[tid + i * 256];
    }
    if (tid < 64) p2.ys[tid] = yts[bi * 64 + tid];

    // (a) reduce pool partials -> xa
    #pragma unroll
    for (int it = 0; it < 3; ++it) {
        int flat = tid + it * 256;
        int hp = flat / 96, f = flat - hp * 96;
        float n = 0.f, d = 0.f;
        #pragma unroll
        for (int cc = 0; cc < 8; ++cc) {
            n += ws[WS_PN + ((size_t)((b * 8 + cc) * 8 + hp)) * 96 + f];
            d += ws[WS_PD + ((size_t)((b * 8 + cc) * 8 + hp)) * 96 + f];
        }
        p2.xa[flat] = n / d;
    }
    __syncthreads();

    // (b) coeff GEMV, 2 items/thread over (h,p,l); ow reads are coalesced
    #pragma unroll
    for (int it = 0; it < 2; ++it) {
        int idx = tid + it * 256;
        int h = idx >> 7, p = (idx >> 6) & 1, l = idx & 63;
        const float* xr = p2.xa + (h * 2 + p) * 96;
        const float* owr = ow + (size_t)(h * 2 * D_) * L_ + l;
        float acc = 0.f;
        #pragma unroll 4
        for (int f = 0; f < 96; ++f)
            acc += xr[f] * owr[(size_t)f * L_];
        p2.cfp[h][p][l] = acc;
    }
    __syncthreads();

    // (c) combine coeff partials + ob + ob2 partials
    if (tid < 128) {
        int p = tid >> 6, l = tid & 63;
        float v = p2.cfp[0][p][l] + p2.cfp[1][p][l] + p2.cfp[2][p][l]
                + p2.cfp[3][p][l] + ob[l];
        #pragma unroll
        for (int g = 0; g < 8; ++g) v += ws[WS_OB2P + g * 64 + l];
        p2.cf[p][l] = v;
    }
    __syncthreads();

    // (d) a0/a1 GEMV, thread = (l-slice, j)
    {
        int s = tid >> 7, j = tid & 127;
        float a0 = 0.f, a1 = 0.f;
        #pragma unroll 4
        for (int li = 0; li < 32; ++li) {
            int l = s * 32 + li;
            float wv = w1[l * HID_ + j];
            a0 += p2.cf[0][l] * wv;
            a1 += p2.cf[1][l] * wv;
        }
        p2.abp[s][0][j] = a0;
        p2.abp[s][1][j] = a1;
    }
    __syncthreads();

    // (e) combine a0/a1 + (f) land w2 prefetch in LDS
    if (tid < 128) {
        p2.a0[tid] = p2.abp[0][0][tid] + p2.abp[1][0][tid] + b1[tid];
    } else {
        int j = tid - 128;
        p2.a1[j] = p2.abp[0][1][j] + p2.abp[1][1][j];
    }
    {
        float4* dst = (float4*)p2.w2s;
        #pragma unroll
        for (int i = 0; i < 12; ++i) dst[tid + i * 256] = wreg[i];
    }
    __syncthreads();

    // (g) decoder: thread = (pos = tid&63, ds = tid>>6); all 64 lanes of a
    // wave share ds -> every w2s/a0/a1 read in the j-loop is wave-uniform
    // (LDS broadcast, conflict-free).
    const int pos = tid & 63, ds = tid >> 6;
    const float y = p2.ys[pos];
    const float* wrow = p2.w2s + ds * 24;

    float acc[24];
    #pragma unroll
    for (int dd = 0; dd < 24; ++dd) acc[dd] = 0.f;

    #pragma unroll 4
    for (int j = 0; j < HID_; ++j) {
        float h = fmaxf(0.f, p2.a0[j] + y * p2.a1[j]);
        const float* wr = wrow + j * D_;
        #pragma unroll
        for (int q = 0; q < 6; ++q) {
            float4 w4 = *(const float4*)(wr + q * 4);
            acc[q * 4 + 0] += h * w4.x;
            acc[q * 4 + 1] += h * w4.y;
            acc[q * 4 + 2] += h * w4.z;
            acc[q * 4 + 3] += h * w4.w;
        }
    }

    float* op = out + ((size_t)(bi * 64 + pos)) * D_ + ds * 24;
    const float* bp = b2 + ds * 24;
    #pragma unroll
    for (int q = 0; q < 6; ++q) {
        float4 v;
        v.x = acc[q * 4 + 0] + bp[q * 4 + 0];
        v.y = acc[q * 4 + 1] + bp[q * 4 + 1];
        v.z = acc[q * 4 + 2] + bp[q * 4 + 2];
        v.w = acc[q * 4 + 3] + bp[q * 4 + 3];
        *(float4*)(op + q * 4) = v;
    }
}

// ---------------------------------------------------------------------------
// Single fused cooperative kernel: 512 blocks x 256 threads, one grid.sync.
// ---------------------------------------------------------------------------
__global__ __launch_bounds__(256) void kfused(
    const float* __restrict__ tsteps, const float* __restrict__ te_w,
    const float* __restrict__ te_b,   const float* __restrict__ X,
    const float* __restrict__ M,      const float* __restrict__ query,
    const float* __restrict__ q_w,    const float* __restrict__ q_b,
    const float* __restrict__ k_w,    const float* __restrict__ k_b,
    const float* __restrict__ ow,     const float* __restrict__ ob,
    const float* __restrict__ w1,     const float* __restrict__ b1,
    const float* __restrict__ yts,    const float* __restrict__ w2,
    const float* __restrict__ b2,     float* __restrict__ ws,
    float* __restrict__ out)
{
    __shared__ SMem sm;
    const int bi = blockIdx.x, tid = threadIdx.x;
    phase1(sm, bi, tid, tsteps, te_w, te_b, X, M, query,
           q_w, q_b, k_w, k_b, ow, ws);
    __threadfence();          // device-scope release of ws partials (x-XCD)
    cg::this_grid().sync();   // grid-wide barrier + acquire
    phase2(sm, bi, tid, ow, ob, w1, b1, yts, w2, b2, ws, out);
}

// ---------------------------------------------------------------------------
// Fallback (non-cooperative) 2-kernel split: identical phases, kernel
// boundary provides the grid-wide sync + memory visibility.
// ---------------------------------------------------------------------------
__global__ __launch_bounds__(256) void kphase1(
    const float* __restrict__ tsteps, const float* __restrict__ te_w,
    const float* __restrict__ te_b,   const float* __restrict__ X,
    const float* __restrict__ M,      const float* __restrict__ query,
    const float* __restrict__ q_w,    const float* __restrict__ q_b,
    const float* __restrict__ k_w,    const float* __restrict__ k_b,
    const float* __restrict__ ow,     float* __restrict__ ws)
{
    __shared__ SMem sm;
    phase1(sm, blockIdx.x, threadIdx.x, tsteps, te_w, te_b, X, M, query,
           q_w, q_b, k_w, k_b, ow, ws);
}

__global__ __launch_bounds__(256) void kphase2(
    const float* __restrict__ ow, const float* __restrict__ ob,
    const float* __restrict__ w1, const float* __restrict__ b1,
    const float* __restrict__ yts, const float* __restrict__ w2,
    const float* __restrict__ b2, const float* __restrict__ ws,
    float* __restrict__ out)
{
    __shared__ SMem sm;
    phase2(sm, blockIdx.x, threadIdx.x, ow, ob, w1, b1, yts, w2, b2, ws, out);
}

// ---------------------------------------------------------------------------
extern "C" void kernel_launch(void* const* d_in, const int* in_sizes, int n_in,
                              void* d_out, int out_size, void* d_ws, size_t ws_size,
                              hipStream_t stream)
{
    const float* timesteps = (const float*)d_in[0];
    const float* X         = (const float*)d_in[1];
    const float* M         = (const float*)d_in[2];
    const float* yts       = (const float*)d_in[3];
    const float* te_w      = (const float*)d_in[4];
    const float* te_b      = (const float*)d_in[5];
    const float* query     = (const float*)d_in[6];
    const float* q_w       = (const float*)d_in[7];
    const float* q_b       = (const float*)d_in[8];
    const float* k_w       = (const float*)d_in[9];
    const float* k_b       = (const float*)d_in[10];
    const float* ow        = (const float*)d_in[11];
    const float* ob        = (const float*)d_in[12];
    const float* w1        = (const float*)d_in[13];
    const float* b1        = (const float*)d_in[14];
    const float* w2        = (const float*)d_in[15];
    const float* b2        = (const float*)d_in[16];
    float* out = (float*)d_out;
    float* ws  = (float*)d_ws;

    void* args[] = {
        (void*)&timesteps, (void*)&te_w, (void*)&te_b, (void*)&X, (void*)&M,
        (void*)&query, (void*)&q_w, (void*)&q_b, (void*)&k_w, (void*)&k_b,
        (void*)&ow, (void*)&ob, (void*)&w1, (void*)&b1, (void*)&yts,
        (void*)&w2, (void*)&b2, (void*)&ws, (void*)&out
    };

    hipError_t err = hipLaunchCooperativeKernel(
        (const void*)kfused, dim3(512), dim3(256), args, 0, stream);
    if (err != hipSuccess) {
        (void)hipGetLastError();  // clear sticky error, use fallback path
        kphase1<<<512, 256, 0, stream>>>(timesteps, te_w, te_b, X, M, query,
                                         q_w, q_b, k_w, k_b, ow, ws);
        kphase2<<<512, 256, 0, stream>>>(ow, ob, w1, b1, yts, w2, b2, ws, out);
    }
}

// Round 2
// 168.573 us; speedup vs baseline: 1.8351x; 1.8351x over previous
//
#include <hip/hip_runtime.h>
#include <math.h>

// Problem constants
#define B_   64
#define T_   512
#define D_   96
#define TY_  512
#define H_   4
#define DK_  32
#define E_   128
#define P_   2
#define L_   64
#define HID_ 128

// Workspace layout (float offsets)
#define WS_OB2P  1024      // 8*64 : ob2 partials (const-half of ow, 8 slices)
#define WS_PN    2048      // 64b*8c*8hp*96f = 393216 : partial numerators
#define WS_PD    395264    // 393216 : partial denominators

// ---------------------------------------------------------------------------
// Kernel 1 (512 blocks = 8 t-chunks x 64 b, 256 thr): prep + scores + exp +
// masked pooling partials.
//   c = bi & 7 (t-chunk), b = bi >> 3 (batch)
//   qm[p,e'] = query[p,:] @ q_w + q_b    (redundant per block, L2-hot)
//   w2q[e,hp] = sum_dk k_w[e,h*32+dk]*qm[p,h*32+dk]/sqrt(32);  bq likewise
// A: w[hp][t] = exp(emb(t) . w2q[:,hp] + bq[hp])   (no max-sub: |s|<~20)
//    NOTE layout [hp][64]: Phase-A lanes (t consecutive) write consecutive
//    addresses -> no bank conflicts (old [t][8] layout was a 16-way
//    conflict, SQ_LDS_BANK_CONFLICT ~1M). Phase-B reads are wave-uniform
//    broadcasts either way.
// B: num[hp,f] += w*M*X ; den[hp,f] += w*M  over the 64-t chunk -> ws
// Epilogue (b==0): ob2 partial slice c (xa 2nd half == 1 -> bias fold)
// ---------------------------------------------------------------------------
__global__ __launch_bounds__(256) void kphase1(
    const float* __restrict__ tsteps, const float* __restrict__ te_w,
    const float* __restrict__ te_b,   const float* __restrict__ X,
    const float* __restrict__ M,      const float* __restrict__ query,
    const float* __restrict__ q_w,    const float* __restrict__ q_b,
    const float* __restrict__ k_w,    const float* __restrict__ k_b,
    const float* __restrict__ ow,     float* __restrict__ ws)
{
    const int bi = blockIdx.x, tid = threadIdx.x;
    const int c = bi & 7, b = bi >> 3;

    __shared__ float qm[P_ * E_];
    __shared__ float w2q_s[E_ * 8];
    __shared__ float tw_s[E_], tb_s[E_], bq_s[8];
    __shared__ float w_s[8][64];        // [hp][t]
    __shared__ float red[96 * 17];      // stride 17: no bank conflicts
    __shared__ float obp2[4][64];

    // ---- Prologue: fused q/k weights ----
    {
        int p = tid >> 7, ep = tid & 127;
        float acc = q_b[ep];
        #pragma unroll 4
        for (int e = 0; e < E_; ++e)
            acc += query[p * E_ + e] * q_w[e * E_ + ep];
        qm[p * E_ + ep] = acc;
    }
    if (tid < E_) { tw_s[tid] = te_w[tid]; tb_s[tid] = te_b[tid]; }
    __syncthreads();
    const float rs = 0.17677669529663687f;  // 1/sqrt(32)
    #pragma unroll
    for (int i = 0; i < 4; ++i) {
        int idx = tid + i * 256;
        int e = idx >> 3, hp = idx & 7, h = hp >> 1, p = hp & 1;
        float acc = 0.f;
        #pragma unroll
        for (int dk = 0; dk < DK_; ++dk)
            acc += k_w[e * E_ + h * DK_ + dk] * qm[p * E_ + h * DK_ + dk];
        w2q_s[idx] = acc * rs;
    }
    if (tid < 8) {
        int hp = tid, h = hp >> 1, p = hp & 1;
        float acc = 0.f;
        #pragma unroll
        for (int dk = 0; dk < DK_; ++dk)
            acc += k_b[h * DK_ + dk] * qm[p * E_ + h * DK_ + dk];
        bq_s[hp] = acc * rs;
    }
    __syncthreads();

    // ---- Phase A: thread = (t in chunk, hp-pair) ----
    {
        const int t = tid & 63, hpg = tid >> 6, hp0 = hpg * 2;
        const float tv = tsteps[b * T_ + c * 64 + t];
        float a0 = 0.f, a1 = 0.f;
        #pragma unroll 4
        for (int e = 0; e < E_; ++e) {
            float v = tv * tw_s[e] + tb_s[e];
            if ((e & 3) == 0) v = __sinf(v);
            float2 w = *(const float2*)&w2q_s[e * 8 + hp0];
            a0 += v * w.x;
            a1 += v * w.y;
        }
        w_s[hp0][t]     = __expf(a0 + bq_s[hp0]);       // lanes: consecutive t
        w_s[hp0 + 1][t] = __expf(a1 + bq_s[hp0 + 1]);   // -> conflict-free
    }
    __syncthreads();

    // ---- Phase B: 2 t-slices x 128 fid (96 active) ----
    const int fid = tid & 127, slice = tid >> 7;
    float num[8] = {0.f, 0.f, 0.f, 0.f, 0.f, 0.f, 0.f, 0.f};
    float den[8] = {0.f, 0.f, 0.f, 0.f, 0.f, 0.f, 0.f, 0.f};
    if (fid < 96) {
        #pragma unroll 4
        for (int i = 0; i < 32; ++i) {
            int tl = slice + 2 * i;           // wave-uniform
            size_t base = ((size_t)(b * T_ + c * 64 + tl)) * D_ + fid;
            float m = M[base], x = X[base];
            float mx = m * x;
            #pragma unroll
            for (int hp = 0; hp < 8; ++hp) {  // w_s[hp][tl]: LDS broadcast
                num[hp] += w_s[hp][tl] * mx;
                den[hp] += w_s[hp][tl] * m;
            }
        }
    }
    __syncthreads();
    if (slice == 1 && fid < 96) {
        #pragma unroll
        for (int hp = 0; hp < 8; ++hp) {
            red[fid * 17 + hp]     = num[hp];
            red[fid * 17 + 8 + hp] = den[hp];
        }
    }
    __syncthreads();
    if (slice == 0 && fid < 96) {
        float* pN = ws + WS_PN + ((size_t)((b * 8 + c) * 8)) * 96;
        float* pD = ws + WS_PD + ((size_t)((b * 8 + c) * 8)) * 96;
        #pragma unroll
        for (int hp = 0; hp < 8; ++hp) {
            pN[hp * 96 + fid] = num[hp] + red[fid * 17 + hp];
            pD[hp * 96 + fid] = den[hp] + red[fid * 17 + 8 + hp];
        }
    }

    // ---- Epilogue (b==0 only): ob2 partial slice c over 48 (h,j) pairs ----
    if (b == 0) {
        int sub = tid >> 6, l = tid & 63;
        float acc = 0.f;
        #pragma unroll
        for (int k = 0; k < 12; ++k) {
            int hj = c * 48 + sub * 12 + k;
            int h = hj / 96, j = hj - h * 96;
            acc += ow[(size_t)(h * 2 * D_ + D_ + j) * L_ + l];
        }
        obp2[sub][l] = acc;
        __syncthreads();
        if (sub == 0)
            ws[WS_OB2P + c * 64 + l] = obp2[0][l] + obp2[1][l]
                                     + obp2[2][l] + obp2[3][l];
    }
}

// ---------------------------------------------------------------------------
// Kernel 2 (512 blocks, 256 thr): partials -> xa -> coeffs -> a0/a1
// (redundant x8 per b — ~50K MACs, cheap, all L2-hot) then the decoder GEMM
// for this block's 64 output positions. w2 is prefetched into registers
// FIRST so the 48 KB global read overlaps the coefficient GEMVs; it lands
// in LDS just before the j-loop needs it. The kernel boundary above is the
// grid-wide sync (graph-captured back-to-back dispatch: ~free, unlike
// cooperative grid.sync which measured ~160 us on this chip).
// ---------------------------------------------------------------------------
__global__ __launch_bounds__(256) void kphase2(
    const float* __restrict__ ow, const float* __restrict__ ob,
    const float* __restrict__ w1, const float* __restrict__ b1,
    const float* __restrict__ yts, const float* __restrict__ w2,
    const float* __restrict__ b2, const float* __restrict__ ws,
    float* __restrict__ out)
{
    __shared__ float w2_s[HID_ * D_];   // 48 KB
    __shared__ float xa_s[8 * 96];
    __shared__ float cfp[4][2][64];
    __shared__ float cf_s[2][64];
    __shared__ float a0_s[HID_], a1_s[HID_];
    __shared__ float y_s[64];
    __shared__ float abp[2][2][128];

    const int bi = blockIdx.x, tid = threadIdx.x;
    const int b = bi >> 3;

    // issue w2 prefetch (12 x float4/thread, coalesced) — consumed at (f)
    float4 wreg[12];
    {
        const float4* src = (const float4*)w2;
        #pragma unroll
        for (int i = 0; i < 12; ++i) wreg[i] = src[tid + i * 256];
    }
    if (tid < 64) y_s[tid] = yts[bi * 64 + tid];

    // (a) reduce pool partials -> xa
    #pragma unroll
    for (int it = 0; it < 3; ++it) {
        int flat = tid + it * 256;
        int hp = flat / 96, f = flat - hp * 96;
        float n = 0.f, d = 0.f;
        #pragma unroll
        for (int cc = 0; cc < 8; ++cc) {
            n += ws[WS_PN + ((size_t)((b * 8 + cc) * 8 + hp)) * 96 + f];
            d += ws[WS_PD + ((size_t)((b * 8 + cc) * 8 + hp)) * 96 + f];
        }
        xa_s[flat] = n / d;
    }
    __syncthreads();

    // (b) coeff GEMV, 2 items/thread over (h,p,l); lanes span l -> each f
    // step reads a contiguous 256 B row of ow (coalesced, L2-hot)
    #pragma unroll
    for (int it = 0; it < 2; ++it) {
        int idx = tid + it * 256;
        int h = idx >> 7, p = (idx >> 6) & 1, l = idx & 63;
        const float* xr = xa_s + (h * 2 + p) * 96;
        const float* owr = ow + (size_t)(h * 2 * D_) * L_ + l;
        float acc = 0.f;
        #pragma unroll 4
        for (int f = 0; f < 96; ++f)
            acc += xr[f] * owr[(size_t)f * L_];
        cfp[h][p][l] = acc;
    }
    __syncthreads();

    // (c) combine coeff partials + ob + ob2 partials
    if (tid < 128) {
        int p = tid >> 6, l = tid & 63;
        float v = cfp[0][p][l] + cfp[1][p][l] + cfp[2][p][l]
                + cfp[3][p][l] + ob[l];
        #pragma unroll
        for (int g = 0; g < 8; ++g) v += ws[WS_OB2P + g * 64 + l];
        cf_s[p][l] = v;
    }
    __syncthreads();

    // (d) a0/a1 GEMV, thread = (l-slice, j)
    {
        int s = tid >> 7, j = tid & 127;
        float a0 = 0.f, a1 = 0.f;
        #pragma unroll 4
        for (int li = 0; li < 32; ++li) {
            int l = s * 32 + li;
            float wv = w1[l * HID_ + j];
            a0 += cf_s[0][l] * wv;
            a1 += cf_s[1][l] * wv;
        }
        abp[s][0][j] = a0;
        abp[s][1][j] = a1;
    }
    __syncthreads();

    // (e) combine a0/a1 + (f) land w2 prefetch in LDS
    if (tid < 128) {
        a0_s[tid] = abp[0][0][tid] + abp[1][0][tid] + b1[tid];
    } else {
        int j = tid - 128;
        a1_s[j] = abp[0][1][j] + abp[1][1][j];
    }
    {
        float4* dst = (float4*)w2_s;
        #pragma unroll
        for (int i = 0; i < 12; ++i) dst[tid + i * 256] = wreg[i];
    }
    __syncthreads();

    // (g) decoder: thread = (pos = tid&63, ds = tid>>6); all 64 lanes of a
    // wave share ds -> every w2_s/a0_s/a1_s read in the j-loop is
    // wave-uniform (LDS broadcast, conflict-free).
    const int pos = tid & 63, ds = tid >> 6;
    const float y = y_s[pos];
    const float* wrow = w2_s + ds * 24;

    float acc[24];
    #pragma unroll
    for (int dd = 0; dd < 24; ++dd) acc[dd] = 0.f;

    #pragma unroll 4
    for (int j = 0; j < HID_; ++j) {
        float h = fmaxf(0.f, a0_s[j] + y * a1_s[j]);
        const float* wr = wrow + j * D_;
        #pragma unroll
        for (int q = 0; q < 6; ++q) {
            float4 w4 = *(const float4*)(wr + q * 4);
            acc[q * 4 + 0] += h * w4.x;
            acc[q * 4 + 1] += h * w4.y;
            acc[q * 4 + 2] += h * w4.z;
            acc[q * 4 + 3] += h * w4.w;
        }
    }

    float* op = out + ((size_t)(bi * 64 + pos)) * D_ + ds * 24;
    const float* bp = b2 + ds * 24;
    #pragma unroll
    for (int q = 0; q < 6; ++q) {
        float4 v;
        v.x = acc[q * 4 + 0] + bp[q * 4 + 0];
        v.y = acc[q * 4 + 1] + bp[q * 4 + 1];
        v.z = acc[q * 4 + 2] + bp[q * 4 + 2];
        v.w = acc[q * 4 + 3] + bp[q * 4 + 3];
        *(float4*)(op + q * 4) = v;
    }
}

// ---------------------------------------------------------------------------
extern "C" void kernel_launch(void* const* d_in, const int* in_sizes, int n_in,
                              void* d_out, int out_size, void* d_ws, size_t ws_size,
                              hipStream_t stream)
{
    const float* timesteps = (const float*)d_in[0];
    const float* X         = (const float*)d_in[1];
    const float* M         = (const float*)d_in[2];
    const float* yts       = (const float*)d_in[3];
    const float* te_w      = (const float*)d_in[4];
    const float* te_b      = (const float*)d_in[5];
    const float* query     = (const float*)d_in[6];
    const float* q_w       = (const float*)d_in[7];
    const float* q_b       = (const float*)d_in[8];
    const float* k_w       = (const float*)d_in[9];
    const float* k_b       = (const float*)d_in[10];
    const float* ow        = (const float*)d_in[11];
    const float* ob        = (const float*)d_in[12];
    const float* w1        = (const float*)d_in[13];
    const float* b1        = (const float*)d_in[14];
    const float* w2        = (const float*)d_in[15];
    const float* b2        = (const float*)d_in[16];
    float* out = (float*)d_out;
    float* ws  = (float*)d_ws;

    kphase1<<<512, 256, 0, stream>>>(timesteps, te_w, te_b, X, M, query,
                                     q_w, q_b, k_w, k_b, ow, ws);
    kphase2<<<512, 256, 0, stream>>>(ow, ob, w1, b1, yts, w2, b2, ws, out);
}